// Round 1
// baseline (203.261 us; speedup 1.0000x reference)
//
#include <hip/hip_runtime.h>

#define GAS __attribute__((address_space(1)))
#define LAS __attribute__((address_space(3)))

typedef short bf16x8 __attribute__((ext_vector_type(8)));
typedef float f32x4  __attribute__((ext_vector_type(4)));

__device__ __forceinline__ short f2bf(float f) {
  __bf16 h = (__bf16)f;                 // RNE, lowers to v_cvt_pk_bf16_f32 on gfx950
  return __builtin_bit_cast(short, h);
}

// ---------------------------------------------------------------------------
// Kernel 1: all 5 skinny GEMMs (4 gate matmuls over K=4096, y over K=2048),
// bf16 MFMA 16x16x32, fp32 accumulate. Partial sums (K-split) to ws.
// ws layout (floats):
//   [0 .. 2097152)   gate partials: ks*524288 + b*8192 + gate*2048 + j   (ks 0..3)
//   [2097152 .. 3145728) y partials: 2097152 + ksy*131072 + b*2048 + j  (ksy 0..7)
// ---------------------------------------------------------------------------
__global__ __launch_bounds__(256, 2) void lstm_gemm(
    const float* __restrict__ X, const float* __restrict__ H,
    const float* __restrict__ Wfh, const float* __restrict__ Wfx, const float* __restrict__ bfp,
    const float* __restrict__ Wih, const float* __restrict__ Wix, const float* __restrict__ bip,
    const float* __restrict__ Woh, const float* __restrict__ Wox, const float* __restrict__ bop,
    const float* __restrict__ Wch, const float* __restrict__ Wcx, const float* __restrict__ bcp,
    const float* __restrict__ Wy,  const float* __restrict__ by,
    float* __restrict__ ws)
{
  __shared__ float lds[2][64 * 128];       // 2 x 32KB chunk buffers (fp32, swizzled)

  const int tid  = threadIdx.x;
  const int lane = tid & 63;
  const int widx = tid >> 6;
  const int w    = blockIdx.x * 4 + widx;  // wave id 0..2047

  // gate job: gate in 0..3 (f,i,c~,o), k-split ks in 0..3, col tile jt
  const int gate = w >> 9;
  const int ks   = (w >> 7) & 3;
  const int jt   = w & 127;
  const int j0   = jt * 16;
  const bool hasY = (w < 1024);            // blocks 0..255 also do a y job
  const int ksy  = (w >> 7) & 7;           // y k-split 0..7

  const int n   = lane & 15;               // fragment col
  const int kg  = lane >> 4;               // k-group 0..3
  const int swz = (n & 7) << 4;            // LDS XOR swizzle (row&7 == n&7)

  const float *Wg_h, *Wg_x, *bg;
  if      (gate == 0) { Wg_h = Wfh; Wg_x = Wfx; bg = bfp; }
  else if (gate == 1) { Wg_h = Wih; Wg_x = Wix; bg = bip; }
  else if (gate == 2) { Wg_h = Wch; Wg_x = Wcx; bg = bcp; }
  else                { Wg_h = Woh; Wg_x = Wox; bg = bop; }

  // job k-range: ks*1024 .. +1024 of the concat(h, x) K axis
  const float* Wjob  = (ks < 2) ? (Wg_h + (size_t)ks * 1024 * 2048)
                                : (Wg_x + (size_t)(ks - 2) * 1024 * 2048);
  const float* Ajob  = (ks < 2) ? (H + ks * 1024) : (X + (ks - 2) * 1024);
  const float* WyJob = Wy + (size_t)ksy * 256 * 2048;
  const float* AyJob = H + ksy * 256;

  f32x4 accA[4], accC[4];
  {
    float ba = (ks  == 0) ? bg[j0 + n] : 0.f;   // bias folded into split 0
    float bcY = (ksy == 0) ? by[j0 + n] : 0.f;
    #pragma unroll
    for (int m = 0; m < 4; ++m) {
      accA[m] = (f32x4){ba, ba, ba, ba};
      accC[m] = (f32x4){bcY, bcY, bcY, bcY};
    }
  }

  // --- stage one 64x128 fp32 A-chunk into LDS buf (wave stages its 16 rows) ---
  auto stage = [&](int buf, const float* srcCol, int kcol) {
    #pragma unroll
    for (int i = 0; i < 8; ++i) {
      const int r  = widx * 16 + i * 2 + (lane >> 5);          // 2 rows / instr
      const int cw = ((lane & 31) ^ (r & 7)) * 4;              // pre-swizzled source
      const float* src = srcCol + (size_t)r * 2048 + kcol + cw;
      float* dst = &lds[buf][(widx * 16 + i * 2) * 128];       // wave-uniform base
      __builtin_amdgcn_global_load_lds((const GAS unsigned*)src,
                                       (LAS unsigned*)dst, 16, 0, 0);
    }
  };

  // --- compute 4 K-steps (128 k) of one chunk against weight rows Wbase ---
  auto computeChunk = [&](int buf, const float* Wbase, f32x4 (&acc)[4]) {
    const char* lbase = (const char*)&lds[buf][0];
    #pragma unroll
    for (int k0 = 0; k0 < 128; k0 += 32) {
      const float* wp = Wbase + (size_t)(k0 + kg * 8) * 2048 + j0 + n;
      bf16x8 bfrag;
      #pragma unroll
      for (int i = 0; i < 8; ++i) bfrag[i] = f2bf(wp[(size_t)i * 2048]);
      const int bir = (k0 + kg * 8) * 4;     // byte offset in LDS row
      #pragma unroll
      for (int m = 0; m < 4; ++m) {
        const int rowb = (m * 16 + n) * 512;
        f32x4 lo = *(const f32x4*)(lbase + rowb + ((bir     ) ^ swz));
        f32x4 hi = *(const f32x4*)(lbase + rowb + ((bir + 16) ^ swz));
        bf16x8 af;
        af[0] = f2bf(lo[0]); af[1] = f2bf(lo[1]); af[2] = f2bf(lo[2]); af[3] = f2bf(lo[3]);
        af[4] = f2bf(hi[0]); af[5] = f2bf(hi[1]); af[6] = f2bf(hi[2]); af[7] = f2bf(hi[3]);
        acc[m] = __builtin_amdgcn_mfma_f32_16x16x32_bf16(af, bfrag, acc[m], 0, 0, 0);
      }
    }
  };

  const int nCC = hasY ? 10 : 8;   // 8 gate chunks (+2 y chunks), block-uniform

  // chunk cc -> staging source
  auto srcOf = [&](int cc, const float*& s, int& kc) {
    if (cc < 8) { s = Ajob;  kc = cc * 128; }
    else        { s = AyJob; kc = (cc - 8) * 128; }
  };

  { const float* s; int kc; srcOf(0, s, kc); stage(0, s, kc); }

  for (int cc = 0; cc < nCC; ++cc) {
    __builtin_amdgcn_s_barrier();            // everyone done reading buf (cc+1)&1
    asm volatile("" ::: "memory");
    if (cc + 1 < nCC) {
      const float* s; int kc; srcOf(cc + 1, s, kc);
      stage((cc + 1) & 1, s, kc);            // prefetch next chunk (8 loads in flight)
      asm volatile("s_waitcnt vmcnt(8)" ::: "memory");   // chunk cc landed
    } else {
      asm volatile("s_waitcnt vmcnt(0)" ::: "memory");
    }
    __builtin_amdgcn_s_barrier();            // chunk cc visible block-wide
    asm volatile("" ::: "memory");

    if (cc < 8) computeChunk(cc & 1, Wjob  + (size_t)(cc * 128) * 2048, accA);
    else        computeChunk(cc & 1, WyJob + (size_t)((cc - 8) * 128) * 2048, accC);

    if (cc == 7) {   // write gate partial: D row = m*16 + kg*4 + r, col = j0+n
      float* base = ws + (size_t)ks * 524288 + (size_t)gate * 2048 + j0 + n;
      #pragma unroll
      for (int m = 0; m < 4; ++m)
        #pragma unroll
        for (int r = 0; r < 4; ++r)
          base[(size_t)(m * 16 + kg * 4 + r) * 8192] = accA[m][r];
    }
    if (cc == 9) {   // write y partial
      float* base = ws + 2097152 + (size_t)ksy * 131072 + j0 + n;
      #pragma unroll
      for (int m = 0; m < 4; ++m)
        #pragma unroll
        for (int r = 0; r < 4; ++r)
          base[(size_t)(m * 16 + kg * 4 + r) * 2048] = accC[m][r];
    }
  }
}

// ---------------------------------------------------------------------------
// Kernel 2: reduce K-split partials, apply LSTM nonlinearity, pack [y|h|c].
// ---------------------------------------------------------------------------
__global__ __launch_bounds__(256) void lstm_combine(
    const float* __restrict__ ws, const float* __restrict__ c_prev,
    float* __restrict__ out)
{
  const int t  = blockIdx.x * 256 + threadIdx.x;  // 0..32767
  const int b  = t >> 9;
  const int j4 = (t & 511) * 4;

  f32x4 g[4];
  #pragma unroll
  for (int gg = 0; gg < 4; ++gg) {
    f32x4 s = (f32x4){0.f, 0.f, 0.f, 0.f};
    #pragma unroll
    for (int ks = 0; ks < 4; ++ks)
      s += *(const f32x4*)(ws + (size_t)ks * 524288 + (size_t)b * 8192 + gg * 2048 + j4);
    g[gg] = s;
  }
  f32x4 ysum = (f32x4){0.f, 0.f, 0.f, 0.f};
  #pragma unroll
  for (int ks = 0; ks < 8; ++ks)
    ysum += *(const f32x4*)(ws + 2097152 + (size_t)ks * 131072 + (size_t)b * 2048 + j4);

  const f32x4 cp = *(const f32x4*)(c_prev + (size_t)b * 2048 + j4);
  f32x4 hF, cF;
  #pragma unroll
  for (int e = 0; e < 4; ++e) {
    float f  = 1.f / (1.f + __expf(-g[0][e]));
    float i  = 1.f / (1.f + __expf(-g[1][e]));
    float ct = tanhf(g[2][e]);
    float o  = 1.f / (1.f + __expf(-g[3][e]));
    float c  = f * cp[e] + i * ct;
    cF[e] = c;
    hF[e] = o * tanhf(c);
  }
  float* ob = out + (size_t)b * 6144;
  *(f32x4*)(ob + j4)        = ysum;   // y = h_prev @ Wy + by
  *(f32x4*)(ob + 2048 + j4) = hF;     // h
  *(f32x4*)(ob + 4096 + j4) = cF;     // c
}

extern "C" void kernel_launch(void* const* d_in, const int* in_sizes, int n_in,
                              void* d_out, int out_size, void* d_ws, size_t ws_size,
                              hipStream_t stream)
{
  const float* X   = (const float*)d_in[0];
  const float* H   = (const float*)d_in[1];
  const float* Cp  = (const float*)d_in[2];
  const float* Wfh = (const float*)d_in[3];
  const float* Wfx = (const float*)d_in[4];
  const float* bfp = (const float*)d_in[5];
  const float* Wih = (const float*)d_in[6];
  const float* Wix = (const float*)d_in[7];
  const float* bip = (const float*)d_in[8];
  const float* Woh = (const float*)d_in[9];
  const float* Wox = (const float*)d_in[10];
  const float* bop = (const float*)d_in[11];
  const float* Wch = (const float*)d_in[12];
  const float* Wcx = (const float*)d_in[13];
  const float* bcp = (const float*)d_in[14];
  const float* Wy  = (const float*)d_in[15];
  const float* by  = (const float*)d_in[16];
  float* ws  = (float*)d_ws;
  float* out = (float*)d_out;

  lstm_gemm<<<512, 256, 0, stream>>>(X, H, Wfh, Wfx, bfp, Wih, Wix, bip,
                                     Woh, Wox, bop, Wch, Wcx, bcp, Wy, by, ws);
  lstm_combine<<<128, 256, 0, stream>>>(ws, Cp, out);
}